// Round 9
// baseline (158.849 us; speedup 1.0000x reference)
//
#include <hip/hip_runtime.h>
#include <math.h>

// SupervisedContrastiveLoss (R9): LDS-free GEMM, register double-buffered B.
//   row_loss_i = log(S_i) - (h_i . csum[lbl_i] - ||h_i||^2) * invT / pos_cnt_i
//   S_i = sum_{lbl_j != lbl_i} exp(s_ij/T)
// R8 post-mortem: barrier-free LDS version stuck at 50us, MfmaUtil 12%, nothing
// saturated -> exposed latency; LDS staging machinery (addr math, ds_read, 1M
// bank conflicts, waitcnt coupling) is pure overhead since hA (4MB) is L2-hot.
// R9: one-wave blocks (64thr x 2048), B loaded global->VGPR one step ahead
// (ping-pong reg buffers, 2x-unrolled loop, no moves); compiler emits fine
// vmcnt(N) keeping prefetch in flight. A (64row x K256) resident in 128 VGPRs.
// Triangle scheme unchanged (R7/R8-proven): strip by = rows [64by,64by+64),
// cols [64by,8192) in 16-col steps; t<4 diagonal -> rowS only; t>=4 -> +colS.

#define NROWS 8192
#define NDIM  256
#define NSTEPS_TOTAL 33024        // sum_by (512 - 4*by), by<128
#define NWAVES 2048
#define INVT 14.285714285714286f  // 1/0.07
#define SC_LOG2E (14.285714285714286f * 1.4426950408889634f)  // invT * log2(e)
#define MASK_BIAS -30000.0f       // exp2 bias for same-label pairs -> exp == 0

typedef __attribute__((ext_vector_type(8))) short short8;
typedef __attribute__((ext_vector_type(4))) float f32x4;

__device__ __forceinline__ unsigned short f2bf(float f) {
    unsigned int u = __float_as_uint(f);
    u = u + 0x7fffu + ((u >> 16) & 1u);     // RNE
    return (unsigned short)(u >> 16);
}
__device__ __forceinline__ float bf2f(unsigned short s) {
    return __uint_as_float(((unsigned int)s) << 16);
}

// ================= prep: normalize -> hA bf16; selfsim; neg=0; csum/cnt partials
__global__ __launch_bounds__(256) void prep_kernel(const float* __restrict__ x,
                                                   const int* __restrict__ labels,
                                                   unsigned short* __restrict__ hA,
                                                   float* __restrict__ selfsim,
                                                   float* __restrict__ neg,
                                                   float* __restrict__ csum_part,
                                                   float* __restrict__ cnt_part,
                                                   int* __restrict__ ticket) {
    __shared__ float sdata[4][2][256];
    __shared__ float cw[4];
    const int tid = threadIdx.x, blk = blockIdx.x;
    const int w = tid >> 6, lane = tid & 63;
    const int row0 = blk * 32;

    float a0[4] = {0.f, 0.f, 0.f, 0.f}, a1[4] = {0.f, 0.f, 0.f, 0.f};
    int c1 = 0;
    for (int i = 0; i < 8; ++i) {
        int row = row0 + w * 8 + i;
        float4 v = *(const float4*)(x + (size_t)row * NDIM + lane * 4);
        float ss = v.x * v.x + v.y * v.y + v.z * v.z + v.w * v.w;
#pragma unroll
        for (int o = 32; o >= 1; o >>= 1) ss += __shfl_xor(ss, o, 64);
        float inv = 1.0f / fmaxf(sqrtf(ss), 1e-12f);
        ushort4 b;
        b.x = f2bf(v.x * inv); b.y = f2bf(v.y * inv);
        b.z = f2bf(v.z * inv); b.w = f2bf(v.w * inv);
        float f0 = bf2f(b.x), f1 = bf2f(b.y), f2 = bf2f(b.z), f3 = bf2f(b.w);
        float s2 = f0 * f0 + f1 * f1 + f2 * f2 + f3 * f3;
#pragma unroll
        for (int o = 32; o >= 1; o >>= 1) s2 += __shfl_xor(s2, o, 64);
        *(ushort4*)(hA + (size_t)row * NDIM + lane * 4) = b;
        if (lane == 0) { selfsim[row] = s2; neg[row] = 0.f; }
        int l = labels[row] & 1;
        c1 += l;
        if (l) { a1[0] += f0; a1[1] += f1; a1[2] += f2; a1[3] += f3; }
        else   { a0[0] += f0; a0[1] += f1; a0[2] += f2; a0[3] += f3; }
    }
#pragma unroll
    for (int k = 0; k < 4; ++k) {
        sdata[w][0][lane * 4 + k] = a0[k];
        sdata[w][1][lane * 4 + k] = a1[k];
    }
    if (lane == 0) cw[w] = (float)c1;
    __syncthreads();
    float s0 = sdata[0][0][tid] + sdata[1][0][tid] + sdata[2][0][tid] + sdata[3][0][tid];
    float s1 = sdata[0][1][tid] + sdata[1][1][tid] + sdata[2][1][tid] + sdata[3][1][tid];
    csum_part[blk * 512 + tid] = s0;
    csum_part[blk * 512 + 256 + tid] = s1;
    if (tid == 0) {
        float c = cw[0] + cw[1] + cw[2] + cw[3];
        cnt_part[blk * 2 + 1] = c;
        cnt_part[blk * 2 + 0] = 32.0f - c;
        if (blk == 0) ticket[0] = 0;
    }
}

// ================= csum finalize: one block, writes csum[512] and cnt[2]
__global__ __launch_bounds__(256) void csumfin_kernel(const float* __restrict__ csum_part,
                                                      const float* __restrict__ cnt_part,
                                                      float* __restrict__ csum,
                                                      float* __restrict__ cnt) {
    const int tid = threadIdx.x;
    float s0 = 0.f, s1 = 0.f;
    for (int b = 0; b < 256; ++b) {
        s0 += csum_part[b * 512 + tid];
        s1 += csum_part[b * 512 + 256 + tid];
    }
    csum[tid] = s0;
    csum[256 + tid] = s1;
    if (tid < 2) {
        float c = 0.f;
        for (int b = 0; b < 256; ++b) c += cnt_part[b * 2 + tid];
        cnt[tid] = c;
    }
}

// ================= LDS-free triangle GEMM, one wave per block
__global__ __launch_bounds__(64, 2) void gemm_kernel(const unsigned short* __restrict__ hA,
                                                     const int* __restrict__ labels,
                                                     float* __restrict__ neg) {
    const int lane = threadIdx.x;
    const int quad = lane >> 4, l15 = lane & 15;
    const int wgid = blockIdx.x;
    const int s0 = (int)((long long)wgid * NSTEPS_TOTAL / NWAVES);
    const int s1 = (int)((long long)(wgid + 1) * NSTEPS_TOTAL / NWAVES);
    if (s0 >= s1) return;

    // locate starting strip: steps before strip by = by*(514-2*by)
    int by = 0;
    while (by < 127 && (by + 1) * (514 - 2 * (by + 1)) <= s0) ++by;
    int t = s0 - by * (514 - 2 * by);

    short8 a[4][8];
    unsigned rl;
    float rowS[4][4];

    auto loadStrip = [&](int row0) {
#pragma unroll
        for (int mt = 0; mt < 4; ++mt)
#pragma unroll
            for (int ki = 0; ki < 8; ++ki)
                a[mt][ki] = *(const short8*)(hA +
                    (size_t)(row0 + mt * 16 + l15) * NDIM + ki * 32 + quad * 8);
        rl = 0;
#pragma unroll
        for (int mt = 0; mt < 4; ++mt)
#pragma unroll
            for (int r = 0; r < 4; ++r)
                rl |= (unsigned)(labels[row0 + mt * 16 + quad * 4 + r] & 1) << (mt * 4 + r);
#pragma unroll
        for (int mt = 0; mt < 4; ++mt)
#pragma unroll
            for (int r = 0; r < 4; ++r) rowS[mt][r] = 0.f;
    };

    auto flushRowS = [&](int row0) {
#pragma unroll
        for (int o = 1; o < 16; o <<= 1)
#pragma unroll
            for (int mt = 0; mt < 4; ++mt)
#pragma unroll
                for (int r = 0; r < 4; ++r)
                    rowS[mt][r] += __shfl_xor(rowS[mt][r], o, 64);
        if (l15 == 0) {
#pragma unroll
            for (int mt = 0; mt < 4; ++mt)
#pragma unroll
                for (int r = 0; r < 4; ++r)
                    atomicAdd(&neg[row0 + mt * 16 + quad * 4 + r], rowS[mt][r]);
        }
    };

    loadStrip(by * 64);

    short8 b0[8], b1[8];
    int cl0 = 0, cl1 = 0;
    {
        const unsigned short* bp = hA + (size_t)(by * 64 + t * 16 + l15) * NDIM + quad * 8;
#pragma unroll
        for (int ki = 0; ki < 8; ++ki) b0[ki] = *(const short8*)(bp + ki * 32);
        cl0 = labels[by * 64 + t * 16 + l15] & 1;
    }

    int s = s0;

#define GEMM_STEP(BC, CLC, BN, CLN)                                                     \
    {                                                                                   \
        const int nst = 512 - 4 * by;                                                   \
        const bool strip_end = (t == nst - 1);                                          \
        const int byn = strip_end ? by + 1 : by;                                        \
        const int tn  = strip_end ? 0 : t + 1;                                          \
        const bool pf = (s + 1 < s1);                                                   \
        if (pf) {                                                                       \
            const unsigned short* bp = hA +                                             \
                (size_t)(byn * 64 + tn * 16 + l15) * NDIM + quad * 8;                   \
            _Pragma("unroll")                                                           \
            for (int ki = 0; ki < 8; ++ki) BN[ki] = *(const short8*)(bp + ki * 32);     \
            CLN = labels[byn * 64 + tn * 16 + l15] & 1;                                 \
        }                                                                               \
        const int col0 = by * 64 + t * 16;                                              \
        const unsigned diff = rl ^ (CLC ? 0xFFFFu : 0u);                                \
        f32x4 acc[4];                                                                   \
        _Pragma("unroll")                                                               \
        for (int mt = 0; mt < 4; ++mt) acc[mt] = (f32x4){0.f, 0.f, 0.f, 0.f};           \
        _Pragma("unroll")                                                               \
        for (int ki = 0; ki < 8; ++ki) {                                                \
            _Pragma("unroll")                                                           \
            for (int mt = 0; mt < 4; ++mt)                                              \
                acc[mt] = __builtin_amdgcn_mfma_f32_16x16x32_bf16(a[mt][ki], BC[ki],    \
                                                                  acc[mt], 0, 0, 0);    \
        }                                                                               \
        float colS = 0.f;                                                               \
        _Pragma("unroll")                                                               \
        for (int mt = 0; mt < 4; ++mt)                                                  \
            _Pragma("unroll")                                                           \
            for (int r = 0; r < 4; ++r) {                                               \
                float bias = ((diff >> (mt * 4 + r)) & 1u) ? 0.f : MASK_BIAS;           \
                float e = exp2f(fmaf(acc[mt][r], SC_LOG2E, bias));                      \
                rowS[mt][r] += e;                                                       \
                colS += e;                                                              \
            }                                                                           \
        if (t >= 4) {                                                                   \
            colS += __shfl_xor(colS, 16, 64);                                           \
            colS += __shfl_xor(colS, 32, 64);                                           \
            if (quad == 0) atomicAdd(&neg[col0 + l15], colS);                           \
        }                                                                               \
        if (strip_end || !pf) {                                                         \
            flushRowS(by * 64);                                                         \
            if (pf) loadStrip(byn * 64);                                                \
        }                                                                               \
        by = byn; t = tn; ++s;                                                          \
        if (!pf) break;                                                                 \
    }

    while (true) {
        GEMM_STEP(b0, cl0, b1, cl1)
        GEMM_STEP(b1, cl1, b0, cl0)
    }
#undef GEMM_STEP
}

// ================= rowloss + ticketed finalize (last block writes out)
__global__ __launch_bounds__(256) void rowloss_kernel(const unsigned short* __restrict__ hA,
                                                      const int* __restrict__ labels,
                                                      const float* __restrict__ neg,
                                                      const float* __restrict__ selfsim,
                                                      const float* __restrict__ csum,
                                                      const float* __restrict__ cnt,
                                                      float* __restrict__ pbuf,
                                                      int* __restrict__ ticket,
                                                      float* __restrict__ out) {
    __shared__ float csumS[2][256];
    __shared__ float red[8];
    __shared__ int lastFlag;
    const int tid = threadIdx.x, blk = blockIdx.x;
    const int w = tid >> 6, lane = tid & 63;

    csumS[0][tid] = csum[tid];
    csumS[1][tid] = csum[256 + tid];
    __syncthreads();
    const float c0v = cnt[0], c1v = cnt[1];

    const int row0 = blk * 128;
    float wsum = 0.f, wcnt = 0.f;
    for (int i = 0; i < 32; ++i) {
        int row = row0 + w * 32 + i;
        int l = labels[row] & 1;
        ushort4 hv = *(const ushort4*)(hA + (size_t)row * NDIM + lane * 4);
        const float* cv = &csumS[l][lane * 4];
        float dot = bf2f(hv.x) * cv[0] + bf2f(hv.y) * cv[1] +
                    bf2f(hv.z) * cv[2] + bf2f(hv.w) * cv[3];
#pragma unroll
        for (int o = 32; o >= 1; o >>= 1) dot += __shfl_xor(dot, o, 64);
        if (lane == 0) {
            float pc = (l ? c1v : c0v) - 1.0f;
            float S = neg[row];
            if (pc > 0.5f) {
                wcnt += 1.f;
                if (S > 0.f)
                    wsum += logf(S) - (dot - selfsim[row]) * INVT / pc;
            }
        }
    }
    if (lane == 0) { red[w] = wsum; red[4 + w] = wcnt; }
    __syncthreads();
    if (tid == 0) {
        atomicExch(&pbuf[blk],      red[0] + red[1] + red[2] + red[3]);
        atomicExch(&pbuf[64 + blk], red[4] + red[5] + red[6] + red[7]);
        __threadfence();
        int old = atomicAdd(ticket, 1);
        lastFlag = (old == 63) ? 1 : 0;
    }
    __syncthreads();
    if (lastFlag && tid < 64) {
        __threadfence();
        float v = atomicAdd(&pbuf[tid], 0.0f);        // device-scope atomic read
        float c = atomicAdd(&pbuf[64 + tid], 0.0f);
#pragma unroll
        for (int o = 32; o >= 1; o >>= 1) {
            v += __shfl_xor(v, o, 64);
            c += __shfl_xor(c, o, 64);
        }
        if (tid == 0) out[0] = (c > 0.f) ? v / c : 0.f;
    }
}

extern "C" void kernel_launch(void* const* d_in, const int* in_sizes, int n_in,
                              void* d_out, int out_size, void* d_ws, size_t ws_size,
                              hipStream_t stream) {
    const float* x = (const float*)d_in[0];
    const int* labels = (const int*)d_in[1];

    unsigned short* hA = (unsigned short*)d_ws;              // N*D bf16 = 4 MB
    float* wsf       = (float*)d_ws;
    float* selfsim   = wsf + (size_t)NROWS * NDIM / 2;       // 8192
    float* neg       = selfsim + NROWS;                      // 8192
    float* csum_part = neg + NROWS;                          // 256*512
    float* cnt_part  = csum_part + 256 * 512;                // 512
    float* csum      = cnt_part + 512;                       // 512
    float* cnt       = csum + 512;                           // 2
    float* pbuf      = cnt + 2;                              // 128
    int*   ticket    = (int*)(pbuf + 128);                   // 1

    prep_kernel<<<256, 256, 0, stream>>>(x, labels, hA, selfsim, neg, csum_part, cnt_part, ticket);
    csumfin_kernel<<<1, 256, 0, stream>>>(csum_part, cnt_part, csum, cnt);
    gemm_kernel<<<NWAVES, 64, 0, stream>>>(hA, labels, neg);
    rowloss_kernel<<<64, 256, 0, stream>>>(hA, labels, neg, selfsim, csum, cnt,
                                           pbuf, ticket, (float*)d_out);
}

// Round 10
// 156.138 us; speedup vs baseline: 1.0174x; 1.0174x over previous
//
#include <hip/hip_runtime.h>
#include <math.h>

// SupervisedContrastiveLoss (R10): R9 GEMM + 2x grid; parallel csumfin.
//   row_loss_i = log(S_i) - (h_i . csum[lbl_i] - ||h_i||^2) * invT / pos_cnt_i
//   S_i = sum_{lbl_j != lbl_i} exp(s_ij/T)
// R9 post-mortem: 3 GEMM structures all ~50us, MfmaUtil*dur ~= MFMA work floor,
// occupancy 17% (5.4 waves/CU) -> latency-exposed, starved for waves. At 128
// VGPR HW supports 16 waves/CU; grid was 2048 (8/CU). R10: 4096 one-wave blocks.
// Also: csumfin was 1 block x 256-deep dependent load chain over 512KB (likely
// ~30us, hidden below the top-5 window) -> 65-block parallel reduce (~3us).

#define NROWS 8192
#define NDIM  256
#define NSTEPS_TOTAL 33024        // sum_by (512 - 4*by), by<128
#define NWAVES 4096
#define INVT 14.285714285714286f  // 1/0.07
#define SC_LOG2E (14.285714285714286f * 1.4426950408889634f)  // invT * log2(e)
#define MASK_BIAS -30000.0f       // exp2 bias for same-label pairs -> exp == 0

typedef __attribute__((ext_vector_type(8))) short short8;
typedef __attribute__((ext_vector_type(4))) float f32x4;

__device__ __forceinline__ unsigned short f2bf(float f) {
    unsigned int u = __float_as_uint(f);
    u = u + 0x7fffu + ((u >> 16) & 1u);     // RNE
    return (unsigned short)(u >> 16);
}
__device__ __forceinline__ float bf2f(unsigned short s) {
    return __uint_as_float(((unsigned int)s) << 16);
}

// ================= prep: normalize -> hA bf16; selfsim; neg=0; csum/cnt partials
__global__ __launch_bounds__(256) void prep_kernel(const float* __restrict__ x,
                                                   const int* __restrict__ labels,
                                                   unsigned short* __restrict__ hA,
                                                   float* __restrict__ selfsim,
                                                   float* __restrict__ neg,
                                                   float* __restrict__ csum_part,
                                                   float* __restrict__ cnt_part,
                                                   int* __restrict__ ticket) {
    __shared__ float sdata[4][2][256];
    __shared__ float cw[4];
    const int tid = threadIdx.x, blk = blockIdx.x;
    const int w = tid >> 6, lane = tid & 63;
    const int row0 = blk * 32;

    float a0[4] = {0.f, 0.f, 0.f, 0.f}, a1[4] = {0.f, 0.f, 0.f, 0.f};
    int c1 = 0;
    for (int i = 0; i < 8; ++i) {
        int row = row0 + w * 8 + i;
        float4 v = *(const float4*)(x + (size_t)row * NDIM + lane * 4);
        float ss = v.x * v.x + v.y * v.y + v.z * v.z + v.w * v.w;
#pragma unroll
        for (int o = 32; o >= 1; o >>= 1) ss += __shfl_xor(ss, o, 64);
        float inv = 1.0f / fmaxf(sqrtf(ss), 1e-12f);
        ushort4 b;
        b.x = f2bf(v.x * inv); b.y = f2bf(v.y * inv);
        b.z = f2bf(v.z * inv); b.w = f2bf(v.w * inv);
        float f0 = bf2f(b.x), f1 = bf2f(b.y), f2 = bf2f(b.z), f3 = bf2f(b.w);
        float s2 = f0 * f0 + f1 * f1 + f2 * f2 + f3 * f3;
#pragma unroll
        for (int o = 32; o >= 1; o >>= 1) s2 += __shfl_xor(s2, o, 64);
        *(ushort4*)(hA + (size_t)row * NDIM + lane * 4) = b;
        if (lane == 0) { selfsim[row] = s2; neg[row] = 0.f; }
        int l = labels[row] & 1;
        c1 += l;
        if (l) { a1[0] += f0; a1[1] += f1; a1[2] += f2; a1[3] += f3; }
        else   { a0[0] += f0; a0[1] += f1; a0[2] += f2; a0[3] += f3; }
    }
#pragma unroll
    for (int k = 0; k < 4; ++k) {
        sdata[w][0][lane * 4 + k] = a0[k];
        sdata[w][1][lane * 4 + k] = a1[k];
    }
    if (lane == 0) cw[w] = (float)c1;
    __syncthreads();
    float s0 = sdata[0][0][tid] + sdata[1][0][tid] + sdata[2][0][tid] + sdata[3][0][tid];
    float s1 = sdata[0][1][tid] + sdata[1][1][tid] + sdata[2][1][tid] + sdata[3][1][tid];
    csum_part[blk * 512 + tid] = s0;
    csum_part[blk * 512 + 256 + tid] = s1;
    if (tid == 0) {
        float c = cw[0] + cw[1] + cw[2] + cw[3];
        cnt_part[blk * 2 + 1] = c;
        cnt_part[blk * 2 + 0] = 32.0f - c;
        if (blk == 0) ticket[0] = 0;
    }
}

// ================= csum finalize (parallel): blocks 0..63 -> 8 dims each,
// 32 threads/dim, 8 parallel strided loads + shuffle reduce. Block 64 -> cnt.
__global__ __launch_bounds__(256) void csumfin_kernel(const float* __restrict__ csum_part,
                                                      const float* __restrict__ cnt_part,
                                                      float* __restrict__ csum,
                                                      float* __restrict__ cnt) {
    const int tid = threadIdx.x, blk = blockIdx.x;
    if (blk < 64) {
        const int dim = blk * 8 + (tid >> 5);    // 0..511 (class*256+d folded)
        const int p = tid & 31;
        float s = 0.f;
#pragma unroll
        for (int k = 0; k < 8; ++k)
            s += csum_part[(size_t)(p + k * 32) * 512 + dim];
#pragma unroll
        for (int o = 1; o < 32; o <<= 1) s += __shfl_xor(s, o, 64);
        if (p == 0) csum[dim] = s;
    } else {
        __shared__ float sd[2][256];
        float c0 = cnt_part[tid * 2], c1 = cnt_part[tid * 2 + 1];
        sd[0][tid] = c0; sd[1][tid] = c1;
        __syncthreads();
        for (int o = 128; o > 0; o >>= 1) {
            if (tid < o) { sd[0][tid] += sd[0][tid + o]; sd[1][tid] += sd[1][tid + o]; }
            __syncthreads();
        }
        if (tid == 0) { cnt[0] = sd[0][0]; cnt[1] = sd[1][0]; }
    }
}

// ================= LDS-free triangle GEMM, one wave per block
__global__ __launch_bounds__(64, 2) void gemm_kernel(const unsigned short* __restrict__ hA,
                                                     const int* __restrict__ labels,
                                                     float* __restrict__ neg) {
    const int lane = threadIdx.x;
    const int quad = lane >> 4, l15 = lane & 15;
    const int wgid = blockIdx.x;
    const int s0 = (int)((long long)wgid * NSTEPS_TOTAL / NWAVES);
    const int s1 = (int)((long long)(wgid + 1) * NSTEPS_TOTAL / NWAVES);
    if (s0 >= s1) return;

    // locate starting strip: steps before strip by = by*(514-2*by)
    int by = 0;
    while (by < 127 && (by + 1) * (514 - 2 * (by + 1)) <= s0) ++by;
    int t = s0 - by * (514 - 2 * by);

    short8 a[4][8];
    unsigned rl;
    float rowS[4][4];

    auto loadStrip = [&](int row0) {
#pragma unroll
        for (int mt = 0; mt < 4; ++mt)
#pragma unroll
            for (int ki = 0; ki < 8; ++ki)
                a[mt][ki] = *(const short8*)(hA +
                    (size_t)(row0 + mt * 16 + l15) * NDIM + ki * 32 + quad * 8);
        rl = 0;
#pragma unroll
        for (int mt = 0; mt < 4; ++mt)
#pragma unroll
            for (int r = 0; r < 4; ++r)
                rl |= (unsigned)(labels[row0 + mt * 16 + quad * 4 + r] & 1) << (mt * 4 + r);
#pragma unroll
        for (int mt = 0; mt < 4; ++mt)
#pragma unroll
            for (int r = 0; r < 4; ++r) rowS[mt][r] = 0.f;
    };

    auto flushRowS = [&](int row0) {
#pragma unroll
        for (int o = 1; o < 16; o <<= 1)
#pragma unroll
            for (int mt = 0; mt < 4; ++mt)
#pragma unroll
                for (int r = 0; r < 4; ++r)
                    rowS[mt][r] += __shfl_xor(rowS[mt][r], o, 64);
        if (l15 == 0) {
#pragma unroll
            for (int mt = 0; mt < 4; ++mt)
#pragma unroll
                for (int r = 0; r < 4; ++r)
                    atomicAdd(&neg[row0 + mt * 16 + quad * 4 + r], rowS[mt][r]);
        }
    };

    loadStrip(by * 64);

    short8 b0[8], b1[8];
    int cl0 = 0, cl1 = 0;
    {
        const unsigned short* bp = hA + (size_t)(by * 64 + t * 16 + l15) * NDIM + quad * 8;
#pragma unroll
        for (int ki = 0; ki < 8; ++ki) b0[ki] = *(const short8*)(bp + ki * 32);
        cl0 = labels[by * 64 + t * 16 + l15] & 1;
    }

    int s = s0;

#define GEMM_STEP(BC, CLC, BN, CLN)                                                     \
    {                                                                                   \
        const int nst = 512 - 4 * by;                                                   \
        const bool strip_end = (t == nst - 1);                                          \
        const int byn = strip_end ? by + 1 : by;                                        \
        const int tn  = strip_end ? 0 : t + 1;                                          \
        const bool pf = (s + 1 < s1);                                                   \
        if (pf) {                                                                       \
            const unsigned short* bp = hA +                                             \
                (size_t)(byn * 64 + tn * 16 + l15) * NDIM + quad * 8;                   \
            _Pragma("unroll")                                                           \
            for (int ki = 0; ki < 8; ++ki) BN[ki] = *(const short8*)(bp + ki * 32);     \
            CLN = labels[byn * 64 + tn * 16 + l15] & 1;                                 \
        }                                                                               \
        const int col0 = by * 64 + t * 16;                                              \
        const unsigned diff = rl ^ (CLC ? 0xFFFFu : 0u);                                \
        f32x4 acc[4];                                                                   \
        _Pragma("unroll")                                                               \
        for (int mt = 0; mt < 4; ++mt) acc[mt] = (f32x4){0.f, 0.f, 0.f, 0.f};           \
        _Pragma("unroll")                                                               \
        for (int ki = 0; ki < 8; ++ki) {                                                \
            _Pragma("unroll")                                                           \
            for (int mt = 0; mt < 4; ++mt)                                              \
                acc[mt] = __builtin_amdgcn_mfma_f32_16x16x32_bf16(a[mt][ki], BC[ki],    \
                                                                  acc[mt], 0, 0, 0);    \
        }                                                                               \
        float colS = 0.f;                                                               \
        _Pragma("unroll")                                                               \
        for (int mt = 0; mt < 4; ++mt)                                                  \
            _Pragma("unroll")                                                           \
            for (int r = 0; r < 4; ++r) {                                               \
                float bias = ((diff >> (mt * 4 + r)) & 1u) ? 0.f : MASK_BIAS;           \
                float e = exp2f(fmaf(acc[mt][r], SC_LOG2E, bias));                      \
                rowS[mt][r] += e;                                                       \
                colS += e;                                                              \
            }                                                                           \
        if (t >= 4) {                                                                   \
            colS += __shfl_xor(colS, 16, 64);                                           \
            colS += __shfl_xor(colS, 32, 64);                                           \
            if (quad == 0) atomicAdd(&neg[col0 + l15], colS);                           \
        }                                                                               \
        if (strip_end || !pf) {                                                         \
            flushRowS(by * 64);                                                         \
            if (pf) loadStrip(byn * 64);                                                \
        }                                                                               \
        by = byn; t = tn; ++s;                                                          \
        if (!pf) break;                                                                 \
    }

    while (true) {
        GEMM_STEP(b0, cl0, b1, cl1)
        GEMM_STEP(b1, cl1, b0, cl0)
    }
#undef GEMM_STEP
}

// ================= rowloss + ticketed finalize (last block writes out)
__global__ __launch_bounds__(256) void rowloss_kernel(const unsigned short* __restrict__ hA,
                                                      const int* __restrict__ labels,
                                                      const float* __restrict__ neg,
                                                      const float* __restrict__ selfsim,
                                                      const float* __restrict__ csum,
                                                      const float* __restrict__ cnt,
                                                      float* __restrict__ pbuf,
                                                      int* __restrict__ ticket,
                                                      float* __restrict__ out) {
    __shared__ float csumS[2][256];
    __shared__ float red[8];
    __shared__ int lastFlag;
    const int tid = threadIdx.x, blk = blockIdx.x;
    const int w = tid >> 6, lane = tid & 63;

    csumS[0][tid] = csum[tid];
    csumS[1][tid] = csum[256 + tid];
    __syncthreads();
    const float c0v = cnt[0], c1v = cnt[1];

    const int row0 = blk * 128;
    float wsum = 0.f, wcnt = 0.f;
    for (int i = 0; i < 32; ++i) {
        int row = row0 + w * 32 + i;
        int l = labels[row] & 1;
        ushort4 hv = *(const ushort4*)(hA + (size_t)row * NDIM + lane * 4);
        const float* cv = &csumS[l][lane * 4];
        float dot = bf2f(hv.x) * cv[0] + bf2f(hv.y) * cv[1] +
                    bf2f(hv.z) * cv[2] + bf2f(hv.w) * cv[3];
#pragma unroll
        for (int o = 32; o >= 1; o >>= 1) dot += __shfl_xor(dot, o, 64);
        if (lane == 0) {
            float pc = (l ? c1v : c0v) - 1.0f;
            float S = neg[row];
            if (pc > 0.5f) {
                wcnt += 1.f;
                if (S > 0.f)
                    wsum += logf(S) - (dot - selfsim[row]) * INVT / pc;
            }
        }
    }
    if (lane == 0) { red[w] = wsum; red[4 + w] = wcnt; }
    __syncthreads();
    if (tid == 0) {
        atomicExch(&pbuf[blk],      red[0] + red[1] + red[2] + red[3]);
        atomicExch(&pbuf[64 + blk], red[4] + red[5] + red[6] + red[7]);
        __threadfence();
        int old = atomicAdd(ticket, 1);
        lastFlag = (old == 63) ? 1 : 0;
    }
    __syncthreads();
    if (lastFlag && tid < 64) {
        __threadfence();
        float v = atomicAdd(&pbuf[tid], 0.0f);        // device-scope atomic read
        float c = atomicAdd(&pbuf[64 + tid], 0.0f);
#pragma unroll
        for (int o = 32; o >= 1; o >>= 1) {
            v += __shfl_xor(v, o, 64);
            c += __shfl_xor(c, o, 64);
        }
        if (tid == 0) out[0] = (c > 0.f) ? v / c : 0.f;
    }
}

extern "C" void kernel_launch(void* const* d_in, const int* in_sizes, int n_in,
                              void* d_out, int out_size, void* d_ws, size_t ws_size,
                              hipStream_t stream) {
    const float* x = (const float*)d_in[0];
    const int* labels = (const int*)d_in[1];

    unsigned short* hA = (unsigned short*)d_ws;              // N*D bf16 = 4 MB
    float* wsf       = (float*)d_ws;
    float* selfsim   = wsf + (size_t)NROWS * NDIM / 2;       // 8192
    float* neg       = selfsim + NROWS;                      // 8192
    float* csum_part = neg + NROWS;                          // 256*512
    float* cnt_part  = csum_part + 256 * 512;                // 512
    float* csum      = cnt_part + 512;                       // 512
    float* cnt       = csum + 512;                           // 2
    float* pbuf      = cnt + 2;                              // 128
    int*   ticket    = (int*)(pbuf + 128);                   // 1

    prep_kernel<<<256, 256, 0, stream>>>(x, labels, hA, selfsim, neg, csum_part, cnt_part, ticket);
    csumfin_kernel<<<65, 256, 0, stream>>>(csum_part, cnt_part, csum, cnt);
    gemm_kernel<<<NWAVES, 64, 0, stream>>>(hA, labels, neg);
    rowloss_kernel<<<64, 256, 0, stream>>>(hA, labels, neg, selfsim, csum, cnt,
                                           pbuf, ticket, (float*)d_out);
}